// Round 8
// baseline (1239.977 us; speedup 1.0000x reference)
//
#include <hip/hip_runtime.h>
#include <hip/hip_bf16.h>

// ---------------------------------------------------------------------------
// CapsuleNet forward. Round 18: route_fused rebuilt barrier-free.
//  R17 post-mortem: 130 us/dispatch, VALUBusy 28.6%, latency-bound from
//  (a) per-jg __syncthreads for the W LDS double-buffer, (b) 192 shfl/jg
//  butterfly reduce, (c) 8-deep fma chains at 2.25 waves/SIMD.
//  Fixes:
//   - W read DIRECT from global (L2-resident 2.95 MB, coalesced uint4/lane,
//     shared across the 32 b-blocks of each ic) -> no W staging, no barriers
//     after the caps stage, LDS 21 KB.
//   - merge-tree reduce: 16 arrays x 64 lanes in 15+2 shfl (bit-reversed
//     store index), vs 96 shfl butterfly. Compile-time indices only.
//   - k-chains split into 2 partials; d-accumulator alternated.
//   - mode split into route0 (c=0.1) / route1 (softmax) kernels.
//  Front-end (conv1/arepack/wrepack2/conv2/squash4) byte-identical to R17.
//
// Workspace (bytes):
//   ht    @ 0           : 52,428,800
//   A2    @ 52,428,800  : 10,616,832 -> 63,045,632
//   caps4 @ 63,045,632  : 37,748,736 -> 100,794,368
//   caps  @ 100,794,368 : 9,437,184  -> 110,231,552
//   Wrb2  @ 110,231,552 : 2,949,120  -> 113,180,672  ([18][10][16][64][8] bf16)
//   spart @ 113,180,672 : 2,949,120  -> 116,129,792  ([18][256][160] f32)
//   vsum  @ 116,129,792 : 163,840    -> 116,293,632  ([256][160] f32)
// ---------------------------------------------------------------------------

typedef __attribute__((ext_vector_type(8))) short short8;
typedef __attribute__((ext_vector_type(4))) float float4v;

__device__ inline float bfu(ushort v){ return __uint_as_float((unsigned)v << 16); }

// conv1: x[256,1,28,28] * w[256,1,9,9] -> h_t[b][pos 400][c 256] bf16
__global__ __launch_bounds__(640) void conv1_kernel(const float* __restrict__ x,
    const float* __restrict__ w, const float* __restrict__ bias,
    __hip_bfloat16* __restrict__ ht){
  __shared__ float img[784];
  __shared__ float wsv[32 * 81];
  __shared__ ushort tile[400 * 33];
  int b = blockIdx.x;
  int og = blockIdx.y;
  int t = threadIdx.x;
  const float* xb = x + (size_t)b * 784;
  for (int idx = t; idx < 784; idx += 640) img[idx] = xb[idx];
  for (int idx = t; idx < 2592; idx += 640) wsv[idx] = w[(size_t)og * 2592 + idx];
  __syncthreads();
  int o_l = t / 20;
  int y   = t - o_l * 20;
  float acc[20];
  #pragma unroll
  for (int i = 0; i < 20; i++) acc[i] = 0.f;
  #pragma unroll
  for (int r = 0; r < 9; r++){
    float row[28];
    const float4* rp = (const float4*)&img[(y + r) * 28];
    #pragma unroll
    for (int q = 0; q < 7; q++){
      float4 v4 = rp[q];
      row[4*q+0]=v4.x; row[4*q+1]=v4.y; row[4*q+2]=v4.z; row[4*q+3]=v4.w;
    }
    #pragma unroll
    for (int s = 0; s < 9; s++){
      float wv = wsv[o_l * 81 + r * 9 + s];
      #pragma unroll
      for (int xx = 0; xx < 20; xx++)
        acc[xx] = fmaf(wv, row[xx + s], acc[xx]);
    }
  }
  float bv = bias[og * 32 + o_l];
  #pragma unroll
  for (int xx = 0; xx < 20; xx++){
    __hip_bfloat16 hv = __float2bfloat16(acc[xx] + bv);
    tile[(y * 20 + xx) * 33 + o_l] = *(ushort*)&hv;
  }
  __syncthreads();
  __hip_bfloat16* hb = ht + (size_t)b * 102400 + og * 32;
  for (int idx = t; idx < 6400; idx += 640){
    int pos = idx >> 4, op = idx & 15;
    unsigned v = (unsigned)tile[pos * 33 + op * 2]
               | ((unsigned)tile[pos * 33 + op * 2 + 1] << 16);
    *(unsigned*)(hb + (size_t)pos * 256 + op * 2) = v;
  }
}

// repack conv2 weights (wave-tiled)
__global__ __launch_bounds__(256) void arepack_kernel(const float* __restrict__ w2,
    ushort* __restrict__ A2s){
  __shared__ float wbuf[64 * 81];
  int o = blockIdx.x;
  int t = threadIdx.x;
  int ow = o >> 6, fo = (o >> 4) & 3, l15 = o & 15;
  size_t obase8 = (size_t)ow * 165888 + (size_t)fo * 64 + (size_t)l15 * 4;
  for (int c0 = 0; c0 < 256; c0 += 64){
    __syncthreads();
    for (int idx = t; idx < 5184; idx += 256)
      wbuf[idx] = w2[(size_t)o * 20736 + (size_t)c0 * 81 + idx];
    __syncthreads();
    for (int idx = t; idx < 2592; idx += 256){
      int rs = idx >> 5;
      int cp = (idx & 31) * 2;
      int cg = c0 + cp;
      int ct = cg >> 5, quad = (cg >> 3) & 3, e = cg & 7;
      __hip_bfloat16 b0 = __float2bfloat16(wbuf[cp * 81 + rs]);
      __hip_bfloat16 b1 = __float2bfloat16(wbuf[(cp + 1) * 81 + rs]);
      unsigned pack = (unsigned)*(ushort*)&b0 | ((unsigned)*(ushort*)&b1 << 16);
      size_t si = (obase8 + (size_t)ct * 256 + (size_t)rs * 2048 + quad) * 8 + e;
      *(unsigned*)(A2s + si) = pack;
    }
  }
}

// W [1152][10][16][8] f32 -> Wrb2 [ic 18][j 10][d 16][il 64][k 8] bf16
__global__ __launch_bounds__(256) void wrepack2_kernel(const float* __restrict__ W,
    ushort* __restrict__ Wrb2){
  int ic = blockIdx.x;   // 0..17
  int j  = blockIdx.y;   // 0..9
  int t = threadIdx.x;
  for (int it = t; it < 1024; it += 256){
    int d = it >> 6, il = it & 63;
    const float* src = W + (size_t)(ic*64 + il)*1280 + j*128 + d*8;
    float4 a = *(const float4*)src;
    float4 b = *(const float4*)(src + 4);
    float vals[8] = {a.x,a.y,a.z,a.w,b.x,b.y,b.z,b.w};
    unsigned p[4];
    #pragma unroll
    for (int e = 0; e < 4; e++){
      __hip_bfloat16 h0 = __float2bfloat16(vals[2*e]);
      __hip_bfloat16 h1 = __float2bfloat16(vals[2*e+1]);
      p[e] = (unsigned)*(ushort*)&h0 | ((unsigned)*(ushort*)&h1 << 16);
    }
    uint4 pv = {p[0], p[1], p[2], p[3]};
    *(uint4*)(Wrb2 + ((((size_t)ic*10 + j)*16 + d)*64 + il)*8) = pv;
  }
}

// conv2 implicit GEMM, 2 images/block (R6-verified, Round-10-exact)
__global__ __launch_bounds__(256, 2) void conv2_mfma_kernel(
    const __hip_bfloat16* __restrict__ ht, const short8* __restrict__ A2,
    float* __restrict__ caps4){
  __shared__ ushort img[2][400 * 40];
  int bx  = blockIdx.x;
  int xcd = bx & 7;
  int kq  = xcd >> 1;
  int p   = ((bx >> 3) << 1) | (xcd & 1);
  int b0  = p * 2;
  int t = threadIdx.x;
  int lane = t & 63;
  int wid  = t >> 6;
  int l15  = lane & 15;
  int quad = lane >> 4;

  int bn[3], slc[3];
  #pragma unroll
  for (int fn = 0; fn < 3; fn++){
    int n = fn * 16 + l15;
    int y = n / 6, xx = n - y * 6;
    if (n >= 36){ y = 0; xx = 0; }
    bn[fn]  = 40 * y + 2 * xx;
    slc[fn] = (quad + 4 * y) % 5;
  }
  const short8* i0p = (const short8*)&img[0][0];
  const short8* i1p = (const short8*)&img[1][0];

  float4v acc[4][6];
  #pragma unroll
  for (int fo = 0; fo < 4; fo++)
    #pragma unroll
    for (int fn = 0; fn < 6; fn++)
      acc[fo][fn] = (float4v){0.f, 0.f, 0.f, 0.f};

  for (int ci = 0; ci < 2; ci++){
    int ct = kq * 2 + ci;
    __syncthreads();
    #pragma unroll
    for (int im = 0; im < 2; im++){
      const __hip_bfloat16* hb = ht + (size_t)(b0 + im) * 102400;
      for (int idx = t; idx < 1600; idx += 256){
        int pp = idx >> 2, q = idx & 3;
        int sl = (q + 2 * (pp / 20)) % 5;
        uint4 v = *(const uint4*)(hb + (size_t)pp * 256 + ct * 32 + q * 8);
        *(uint4*)&img[im][pp * 40 + sl * 8] = v;
      }
    }
    __syncthreads();

    const short8* ap = A2 + ((size_t)wid * 648 + ct) * 256 + l15 * 4 + quad;

    short8 aF[2][4], bF[2][6];
    #pragma unroll
    for (int fo = 0; fo < 4; fo++) aF[0][fo] = ap[fo * 64];
    #pragma unroll
    for (int fn = 0; fn < 6; fn++){
      int f3 = (fn < 3) ? fn : fn - 3;
      const short8* ib = (fn < 3) ? i0p : i1p;
      bF[0][fn] = ib[bn[f3] * 5 + slc[f3]];
    }

    int rn = 0, sn = 0, r2m = 0;
    #pragma unroll 2
    for (int rs = 0; rs < 81; rs++){
      int cur = rs & 1, nxt = cur ^ 1;
      sn++;
      if (sn == 9){ sn = 0; rn++; r2m += 2; if (r2m >= 5) r2m -= 5; }
      int nrs = (rs < 80) ? rs + 1 : 80;
      int roff = rn * 20 + sn;
      const short8* apn = ap + (size_t)nrs * 2048;
      #pragma unroll
      for (int fo = 0; fo < 4; fo++) aF[nxt][fo] = apn[fo * 64];
      #pragma unroll
      for (int fn = 0; fn < 6; fn++){
        int f3 = (fn < 3) ? fn : fn - 3;
        const short8* ib = (fn < 3) ? i0p : i1p;
        int sl = slc[f3] + r2m; if (sl >= 5) sl -= 5;
        bF[nxt][fn] = ib[(bn[f3] + roff) * 5 + sl];
      }
      #pragma unroll
      for (int fo = 0; fo < 4; fo++)
        #pragma unroll
        for (int fn = 0; fn < 6; fn++)
          acc[fo][fn] = __builtin_amdgcn_mfma_f32_16x16x32_bf16(aF[cur][fo], bF[cur][fn], acc[fo][fn], 0, 0, 0);
    }
  }

  #pragma unroll
  for (int fn = 0; fn < 6; fn++){
    int im = (fn < 3) ? 0 : 1;
    int f3 = (fn < 3) ? fn : fn - 3;
    int pos = f3 * 16 + l15;
    if (pos < 36){
      float* cb = caps4 + ((size_t)kq * 256 + b0 + im) * 9216;
      #pragma unroll
      for (int fo = 0; fo < 4; fo++){
        int ob = wid * 64 + fo * 16 + quad * 4;
        #pragma unroll
        for (int rr = 0; rr < 4; rr++)
          cb[(size_t)(ob + rr) * 36 + pos] = acc[fo][fn][rr];
      }
    }
  }
}

// sum 4 kq-partials + bias, squash -> caps [b][i][8] fp32
__global__ __launch_bounds__(256) void squash4_kernel(const float* __restrict__ caps4,
    const float* __restrict__ bias, float* __restrict__ caps){
  size_t cid = (size_t)blockIdx.x * 256 + threadIdx.x;
  size_t base = cid * 8;
  const size_t STR = 2359296;
  float4 a0 = *(const float4*)(caps4 + base);
  float4 a1 = *(const float4*)(caps4 + base + 4);
  #pragma unroll
  for (int k = 1; k < 4; k++){
    float4 q0 = *(const float4*)(caps4 + k * STR + base);
    float4 q1 = *(const float4*)(caps4 + k * STR + base + 4);
    a0.x+=q0.x; a0.y+=q0.y; a0.z+=q0.z; a0.w+=q0.w;
    a1.x+=q1.x; a1.y+=q1.y; a1.z+=q1.z; a1.w+=q1.w;
  }
  int off = (int)(base % 9216);
  float v[8] = {a0.x,a0.y,a0.z,a0.w,a1.x,a1.y,a1.z,a1.w};
  #pragma unroll
  for (int e = 0; e < 8; e++) v[e] += bias[(off + e) / 36];
  float msq = 0.f;
  #pragma unroll
  for (int e = 0; e < 8; e++) msq += v[e]*v[e];
  float scale = sqrtf(msq) / (1.f + msq);
  float* cp = caps + base;
  #pragma unroll
  for (int e = 0; e < 8; e++) cp[e] = v[e]*scale;
}

// merge-tree reduce: tv[16] per-lane arrays summed across 64 lanes.
// Returns (on every lane) the sum of array bitrev4(lane&15).
__device__ __forceinline__ float mr16(float* tv, int lane){
  #pragma unroll
  for (int st = 0; st < 4; st++){
    const int m = 1 << st;
    const int half = 8 >> st;
    bool hi = (lane & m) != 0;
    #pragma unroll
    for (int j = 0; j < half; j++){
      float keep = hi ? tv[half + j] : tv[j];
      float send = hi ? tv[j] : tv[half + j];
      float recv = __shfl_xor(send, m);
      tv[j] = keep + recv;
    }
  }
  float s = tv[0];
  s += __shfl_xor(s, 16);
  s += __shfl_xor(s, 32);
  return s;
}

__device__ __forceinline__ int bitrev4(int l){
  return ((l & 1) << 3) | ((l & 2) << 1) | ((l & 4) >> 1) | ((l & 8) >> 3);
}

__device__ __forceinline__ void unpack8(uint4 wv, float* wk){
  wk[0]=bfu((ushort)(wv.x&0xffffu)); wk[1]=bfu((ushort)(wv.x>>16));
  wk[2]=bfu((ushort)(wv.y&0xffffu)); wk[3]=bfu((ushort)(wv.y>>16));
  wk[4]=bfu((ushort)(wv.z&0xffffu)); wk[5]=bfu((ushort)(wv.z>>16));
  wk[6]=bfu((ushort)(wv.w&0xffffu)); wk[7]=bfu((ushort)(wv.w>>16));
}

// routing iteration 0: c = 0.1 uniform. Block: 64 i (lane) x 8 b (2/wave).
// W read direct from global (L2-resident); no barriers after caps stage.
__global__ __launch_bounds__(256) void route0_kernel(
    const float* __restrict__ caps, const ushort* __restrict__ Wrb2,
    float* __restrict__ spart){
  __shared__ float cl[8 * 8 * 64];      // [k][bb][il] 16 KB
  int ic = blockIdx.x;        // 0..17
  int b0 = blockIdx.y * 8;    // 0..248
  int t = threadIdx.x, lane = t & 63, wid = t >> 6;
  int bbA = wid * 2, bbB = bbA + 1;

  for (int f = t; f < 1024; f += 256){
    int base = f * 4; int bb = base >> 9; int r = base & 511;
    int il = r >> 3; int k = r & 7;
    float4 v = *(const float4*)(caps + ((size_t)(b0+bb)*1152 + ic*64 + il)*8 + k);
    cl[((k+0)*8+bb)*64+il] = v.x;
    cl[((k+1)*8+bb)*64+il] = v.y;
    cl[((k+2)*8+bb)*64+il] = v.z;
    cl[((k+3)*8+bb)*64+il] = v.w;
  }
  __syncthreads();

  float clrA[8], clrB[8];
  #pragma unroll
  for (int k = 0; k < 8; k++){
    clrA[k] = cl[(k*8 + bbA)*64 + lane];
    clrB[k] = cl[(k*8 + bbB)*64 + lane];
  }

  const uint4* wic = (const uint4*)Wrb2 + (size_t)ic * 10240 + lane;
  int br = bitrev4(lane & 15);
  float* spA = spart + ((size_t)ic*256 + b0 + bbA)*160;
  float* spB = spart + ((size_t)ic*256 + b0 + bbB)*160;

  for (int jg = 0; jg < 10; jg++){
    const uint4* wjg = wic + jg * 1024;
    float tA[16], tB[16];
    #pragma unroll
    for (int jdl = 0; jdl < 16; jdl++){
      uint4 wv = wjg[jdl * 64];
      float wk[8]; unpack8(wv, wk);
      float a0 = wk[0]*clrA[0], a1 = wk[4]*clrA[4];
      float b0f = wk[0]*clrB[0], b1f = wk[4]*clrB[4];
      #pragma unroll
      for (int k = 1; k < 4; k++){
        a0 = fmaf(wk[k], clrA[k], a0);  a1 = fmaf(wk[k+4], clrA[k+4], a1);
        b0f = fmaf(wk[k], clrB[k], b0f); b1f = fmaf(wk[k+4], clrB[k+4], b1f);
      }
      tA[jdl] = 0.1f * (a0 + a1);
      tB[jdl] = 0.1f * (b0f + b1f);
    }
    float sA = mr16(tA, lane);
    float sB = mr16(tB, lane);
    if (lane < 16){
      spA[jg*16 + br] = sA;
      spB[jg*16 + br] = sB;
    }
  }
}

// routing iterations 1/2: c = softmax_j(u_hat . Vsum). Two sweeps, no
// barriers after staging; W direct from global.
__global__ __launch_bounds__(256) void route1_kernel(
    const float* __restrict__ caps, const ushort* __restrict__ Wrb2,
    const float* __restrict__ vsum, float* __restrict__ spart){
  __shared__ float cl[8 * 8 * 64];      // 16 KB
  __shared__ float vsl[8 * 160];        // 5 KB
  int ic = blockIdx.x;
  int b0 = blockIdx.y * 8;
  int t = threadIdx.x, lane = t & 63, wid = t >> 6;
  int bbA = wid * 2, bbB = bbA + 1;

  for (int f = t; f < 1024; f += 256){
    int base = f * 4; int bb = base >> 9; int r = base & 511;
    int il = r >> 3; int k = r & 7;
    float4 v = *(const float4*)(caps + ((size_t)(b0+bb)*1152 + ic*64 + il)*8 + k);
    cl[((k+0)*8+bb)*64+il] = v.x;
    cl[((k+1)*8+bb)*64+il] = v.y;
    cl[((k+2)*8+bb)*64+il] = v.z;
    cl[((k+3)*8+bb)*64+il] = v.w;
  }
  for (int f = t; f < 1280; f += 256) vsl[f] = vsum[(size_t)b0 * 160 + f];
  __syncthreads();

  float clrA[8], clrB[8];
  #pragma unroll
  for (int k = 0; k < 8; k++){
    clrA[k] = cl[(k*8 + bbA)*64 + lane];
    clrB[k] = cl[(k*8 + bbB)*64 + lane];
  }

  const uint4* wic = (const uint4*)Wrb2 + (size_t)ic * 10240 + lane;
  int br = bitrev4(lane & 15);
  float* spA = spart + ((size_t)ic*256 + b0 + bbA)*160;
  float* spB = spart + ((size_t)ic*256 + b0 + bbB)*160;
  const float* vA = &vsl[bbA * 160];
  const float* vB = &vsl[bbB * 160];

  float m0 = -1e30f, m1 = -1e30f, z0 = 0.f, z1 = 0.f;

  // sweep 1: online softmax stats
  for (int jg = 0; jg < 10; jg++){
    const uint4* wjg = wic + jg * 1024;
    float daE = 0.f, daO = 0.f, dbE = 0.f, dbO = 0.f;
    #pragma unroll
    for (int jdl = 0; jdl < 16; jdl++){
      uint4 wv = wjg[jdl * 64];
      float wk[8]; unpack8(wv, wk);
      float a0 = wk[0]*clrA[0], a1 = wk[4]*clrA[4];
      float b0f = wk[0]*clrB[0], b1f = wk[4]*clrB[4];
      #pragma unroll
      for (int k = 1; k < 4; k++){
        a0 = fmaf(wk[k], clrA[k], a0);  a1 = fmaf(wk[k+4], clrA[k+4], a1);
        b0f = fmaf(wk[k], clrB[k], b0f); b1f = fmaf(wk[k+4], clrB[k+4], b1f);
      }
      float uA = a0 + a1, uB = b0f + b1f;
      float va = vA[jg*16 + jdl], vb = vB[jg*16 + jdl];
      if (jdl & 1){ daO = fmaf(uA, va, daO); dbO = fmaf(uB, vb, dbO); }
      else        { daE = fmaf(uA, va, daE); dbE = fmaf(uB, vb, dbE); }
    }
    float da = daE + daO, db = dbE + dbO;
    float n0 = fmaxf(m0, da);
    z0 = z0 * __expf(m0 - n0) + __expf(da - n0);
    m0 = n0;
    float n1 = fmaxf(m1, db);
    z1 = z1 * __expf(m1 - n1) + __expf(db - n1);
    m1 = n1;
  }
  float iz0 = 1.f / z0, iz1 = 1.f / z1;

  // sweep 2: weighted partials
  for (int jg = 0; jg < 10; jg++){
    const uint4* wjg = wic + jg * 1024;
    float u0[16], u1[16];
    float daE = 0.f, daO = 0.f, dbE = 0.f, dbO = 0.f;
    #pragma unroll
    for (int jdl = 0; jdl < 16; jdl++){
      uint4 wv = wjg[jdl * 64];
      float wk[8]; unpack8(wv, wk);
      float a0 = wk[0]*clrA[0], a1 = wk[4]*clrA[4];
      float b0f = wk[0]*clrB[0], b1f = wk[4]*clrB[4];
      #pragma unroll
      for (int k = 1; k < 4; k++){
        a0 = fmaf(wk[k], clrA[k], a0);  a1 = fmaf(wk[k+4], clrA[k+4], a1);
        b0f = fmaf(wk[k], clrB[k], b0f); b1f = fmaf(wk[k+4], clrB[k+4], b1f);
      }
      float uA = a0 + a1, uB = b0f + b1f;
      u0[jdl] = uA; u1[jdl] = uB;
      float va = vA[jg*16 + jdl], vb = vB[jg*16 + jdl];
      if (jdl & 1){ daO = fmaf(uA, va, daO); dbO = fmaf(uB, vb, dbO); }
      else        { daE = fmaf(uA, va, daE); dbE = fmaf(uB, vb, dbE); }
    }
    float cv0 = __expf((daE + daO) - m0) * iz0;
    float cv1 = __expf((dbE + dbO) - m1) * iz1;
    #pragma unroll
    for (int jdl = 0; jdl < 16; jdl++){
      u0[jdl] *= cv0;
      u1[jdl] *= cv1;
    }
    float sA = mr16(u0, lane);
    float sB = mr16(u1, lane);
    if (lane < 16){
      spA[jg*16 + br] = sA;
      spB[jg*16 + br] = sB;
    }
  }
}

// sum 18 chunk partials + bias, squash over 16-groups.
// mode 0: vsum = v; 1: vsum += v; 2: out = v (final).
__global__ __launch_bounds__(160) void vsqF_kernel(const float* __restrict__ spart,
    const float* __restrict__ dcb, float* __restrict__ vsum,
    float* __restrict__ out, int mode){
  int b = blockIdx.x;
  int t = threadIdx.x;   // 0..159
  float s = dcb[t];
  #pragma unroll
  for (int c = 0; c < 18; c++) s += spart[((size_t)c * 256 + b) * 160 + t];
  float msq = s * s;
  msq += __shfl_xor(msq, 1, 16);
  msq += __shfl_xor(msq, 2, 16);
  msq += __shfl_xor(msq, 4, 16);
  msq += __shfl_xor(msq, 8, 16);
  float scale = sqrtf(msq) / (1.f + msq);
  float v = s * scale;
  if (mode == 2)      out[b * 160 + t] = v;
  else if (mode == 1) vsum[b * 160 + t] += v;
  else                vsum[b * 160 + t] = v;
}

extern "C" void kernel_launch(void* const* d_in, const int* in_sizes, int n_in,
                              void* d_out, int out_size, void* d_ws, size_t ws_size,
                              hipStream_t stream){
  (void)in_sizes; (void)n_in; (void)out_size; (void)ws_size;
  const float* x   = (const float*)d_in[0];
  const float* w1  = (const float*)d_in[1];
  const float* b1  = (const float*)d_in[2];
  const float* w2  = (const float*)d_in[3];
  const float* b2  = (const float*)d_in[4];
  const float* W   = (const float*)d_in[5];
  const float* dcb = (const float*)d_in[6];
  float* out = (float*)d_out;

  char* ws = (char*)d_ws;
  __hip_bfloat16* ht = (__hip_bfloat16*)(ws);
  ushort* A2s  = (ushort*)(ws + 52428800);
  float* caps4 = (float*)(ws + 63045632);
  float* caps  = (float*)(ws + 100794368);
  ushort* Wrb2 = (ushort*)(ws + 110231552);
  float* spart = (float*)(ws + 113180672);
  float* vsum  = (float*)(ws + 116129792);

  conv1_kernel<<<dim3(256, 8), 640, 0, stream>>>(x, w1, b1, ht);
  arepack_kernel<<<256, 256, 0, stream>>>(w2, A2s);
  wrepack2_kernel<<<dim3(18, 10), 256, 0, stream>>>(W, Wrb2);
  conv2_mfma_kernel<<<512, 256, 0, stream>>>(ht, (const short8*)A2s, caps4);
  squash4_kernel<<<1152, 256, 0, stream>>>(caps4, b2, caps);

  route0_kernel<<<dim3(18, 32), 256, 0, stream>>>(caps, Wrb2, spart);
  vsqF_kernel<<<256, 160, 0, stream>>>(spart, dcb, vsum, out, 0);
  route1_kernel<<<dim3(18, 32), 256, 0, stream>>>(caps, Wrb2, vsum, spart);
  vsqF_kernel<<<256, 160, 0, stream>>>(spart, dcb, vsum, out, 1);
  route1_kernel<<<dim3(18, 32), 256, 0, stream>>>(caps, Wrb2, vsum, spart);
  vsqF_kernel<<<256, 160, 0, stream>>>(spart, dcb, vsum, out, 2);
}

// Round 9
// 416.510 us; speedup vs baseline: 2.9771x; 2.9771x over previous
//
#include <hip/hip_runtime.h>
#include <hip/hip_bf16.h>

// ---------------------------------------------------------------------------
// CapsuleNet forward. Round 19: full revert to the Round-0 pipeline (best
// verified total, 398 us). Post-mortems:
//  - R11-13 conv2 1-image rework: latency-bound on A2 stream, 421 us (revert).
//  - R14 uhat_t-fused column sums: +45 us net (shfl chains in a streaming
//    store loop).
//  - R15-18 route_fused/route0/route1 (uT eliminated): correct (absmax
//    0.004) but latency-bound at 576 blocks; 130 -> 359 us per dispatch
//    across two redesigns. Total regressed 398 -> 436 -> 602 -> 1240.
// Conclusion: the uT-materialized routing back-end, despite ~500 MB of
// L2/HBM traffic, beats every fused alternative because it runs wide
// (768-1152 blocks) at near-BW with good occupancy. conv2 (114 us,
// MfmaUtil 52%) is the only dispatch >100 us; its 2-image/128-output
// structure is load-balance-tuned and every perturbation regressed.
//
// Workspace (bytes), total ~125.6 MB:
//   ht    @ 0           : 52,428,800  (conv phase)
//   A2    @ 52,428,800  : 10,616,832 -> 63,045,632
//   caps4 @ 63,045,632  : 37,748,736 -> 100,794,368
//   uT    @ 0           : 94,371,840  (overlays ht/A2/caps4)
//   caps  @ 100,794,368 : 9,437,184  -> 110,231,552
//   Wrb   @ 110,231,552 : 2,949,120  -> 113,180,672
//   bbuf  @ 113,180,672 : 11,796,480 -> 124,977,152
//   spart @ 124,977,152 : 491,520    -> 125,468,672
//   vbuf  @ 125,468,672 : 163,840    -> 125,632,512
// ---------------------------------------------------------------------------

typedef __attribute__((ext_vector_type(8))) short short8;
typedef __attribute__((ext_vector_type(4))) float float4v;

__device__ inline float bfu(ushort v){ return __uint_as_float((unsigned)v << 16); }

// conv1: x[256,1,28,28] * w[256,1,9,9] -> h_t[b][pos 400][c 256] bf16
__global__ __launch_bounds__(640) void conv1_kernel(const float* __restrict__ x,
    const float* __restrict__ w, const float* __restrict__ bias,
    __hip_bfloat16* __restrict__ ht){
  __shared__ float img[784];
  __shared__ float wsv[32 * 81];
  __shared__ ushort tile[400 * 33];
  int b = blockIdx.x;
  int og = blockIdx.y;
  int t = threadIdx.x;
  const float* xb = x + (size_t)b * 784;
  for (int idx = t; idx < 784; idx += 640) img[idx] = xb[idx];
  for (int idx = t; idx < 2592; idx += 640) wsv[idx] = w[(size_t)og * 2592 + idx];
  __syncthreads();
  int o_l = t / 20;
  int y   = t - o_l * 20;
  float acc[20];
  #pragma unroll
  for (int i = 0; i < 20; i++) acc[i] = 0.f;
  #pragma unroll
  for (int r = 0; r < 9; r++){
    float row[28];
    const float4* rp = (const float4*)&img[(y + r) * 28];
    #pragma unroll
    for (int q = 0; q < 7; q++){
      float4 v4 = rp[q];
      row[4*q+0]=v4.x; row[4*q+1]=v4.y; row[4*q+2]=v4.z; row[4*q+3]=v4.w;
    }
    #pragma unroll
    for (int s = 0; s < 9; s++){
      float wv = wsv[o_l * 81 + r * 9 + s];
      #pragma unroll
      for (int xx = 0; xx < 20; xx++)
        acc[xx] = fmaf(wv, row[xx + s], acc[xx]);
    }
  }
  float bv = bias[og * 32 + o_l];
  #pragma unroll
  for (int xx = 0; xx < 20; xx++){
    __hip_bfloat16 hv = __float2bfloat16(acc[xx] + bv);
    tile[(y * 20 + xx) * 33 + o_l] = *(ushort*)&hv;
  }
  __syncthreads();
  __hip_bfloat16* hb = ht + (size_t)b * 102400 + og * 32;
  for (int idx = t; idx < 6400; idx += 640){
    int pos = idx >> 4, op = idx & 15;
    unsigned v = (unsigned)tile[pos * 33 + op * 2]
               | ((unsigned)tile[pos * 33 + op * 2 + 1] << 16);
    *(unsigned*)(hb + (size_t)pos * 256 + op * 2) = v;
  }
}

// repack conv2 weights (wave-tiled)
__global__ __launch_bounds__(256) void arepack_kernel(const float* __restrict__ w2,
    ushort* __restrict__ A2s){
  __shared__ float wbuf[64 * 81];
  int o = blockIdx.x;
  int t = threadIdx.x;
  int ow = o >> 6, fo = (o >> 4) & 3, l15 = o & 15;
  size_t obase8 = (size_t)ow * 165888 + (size_t)fo * 64 + (size_t)l15 * 4;
  for (int c0 = 0; c0 < 256; c0 += 64){
    __syncthreads();
    for (int idx = t; idx < 5184; idx += 256)
      wbuf[idx] = w2[(size_t)o * 20736 + (size_t)c0 * 81 + idx];
    __syncthreads();
    for (int idx = t; idx < 2592; idx += 256){
      int rs = idx >> 5;
      int cp = (idx & 31) * 2;
      int cg = c0 + cp;
      int ct = cg >> 5, quad = (cg >> 3) & 3, e = cg & 7;
      __hip_bfloat16 b0 = __float2bfloat16(wbuf[cp * 81 + rs]);
      __hip_bfloat16 b1 = __float2bfloat16(wbuf[(cp + 1) * 81 + rs]);
      unsigned pack = (unsigned)*(ushort*)&b0 | ((unsigned)*(ushort*)&b1 << 16);
      size_t si = (obase8 + (size_t)ct * 256 + (size_t)rs * 2048 + quad) * 8 + e;
      *(unsigned*)(A2s + si) = pack;
    }
  }
}

// W [1152][1280] f32 -> Wrb [1280][1152] bf16 (transposed)
__global__ __launch_bounds__(256) void wrepack_kernel(const float* __restrict__ W,
    ushort* __restrict__ Wrb){
  __shared__ float tile[64][65];
  int r0 = blockIdx.x * 64;  // i
  int c0 = blockIdx.y * 64;  // jdk
  int t = threadIdx.x; int lx = t & 63, ly = t >> 6;
  for (int rr = ly; rr < 64; rr += 4)
    tile[rr][lx] = W[(size_t)(r0 + rr) * 1280 + c0 + lx];
  __syncthreads();
  for (int rr = ly; rr < 64; rr += 4){
    __hip_bfloat16 hv = __float2bfloat16(tile[lx][rr]);
    Wrb[(size_t)(c0 + rr) * 1152 + r0 + lx] = *(ushort*)&hv;
  }
}

// conv2 implicit GEMM, 2 images/block (R6-verified)
__global__ __launch_bounds__(256, 2) void conv2_mfma_kernel(
    const __hip_bfloat16* __restrict__ ht, const short8* __restrict__ A2,
    float* __restrict__ caps4){
  __shared__ ushort img[2][400 * 40];
  int bx  = blockIdx.x;
  int xcd = bx & 7;
  int kq  = xcd >> 1;
  int p   = ((bx >> 3) << 1) | (xcd & 1);
  int b0  = p * 2;
  int t = threadIdx.x;
  int lane = t & 63;
  int wid  = t >> 6;
  int l15  = lane & 15;
  int quad = lane >> 4;

  int bn[3], slc[3];
  #pragma unroll
  for (int fn = 0; fn < 3; fn++){
    int n = fn * 16 + l15;
    int y = n / 6, xx = n - y * 6;
    if (n >= 36){ y = 0; xx = 0; }
    bn[fn]  = 40 * y + 2 * xx;
    slc[fn] = (quad + 4 * y) % 5;
  }
  const short8* i0p = (const short8*)&img[0][0];
  const short8* i1p = (const short8*)&img[1][0];

  float4v acc[4][6];
  #pragma unroll
  for (int fo = 0; fo < 4; fo++)
    #pragma unroll
    for (int fn = 0; fn < 6; fn++)
      acc[fo][fn] = (float4v){0.f, 0.f, 0.f, 0.f};

  for (int ci = 0; ci < 2; ci++){
    int ct = kq * 2 + ci;
    __syncthreads();
    #pragma unroll
    for (int im = 0; im < 2; im++){
      const __hip_bfloat16* hb = ht + (size_t)(b0 + im) * 102400;
      for (int idx = t; idx < 1600; idx += 256){
        int pp = idx >> 2, q = idx & 3;
        int sl = (q + 2 * (pp / 20)) % 5;
        uint4 v = *(const uint4*)(hb + (size_t)pp * 256 + ct * 32 + q * 8);
        *(uint4*)&img[im][pp * 40 + sl * 8] = v;
      }
    }
    __syncthreads();

    const short8* ap = A2 + ((size_t)wid * 648 + ct) * 256 + l15 * 4 + quad;

    short8 aF[2][4], bF[2][6];
    #pragma unroll
    for (int fo = 0; fo < 4; fo++) aF[0][fo] = ap[fo * 64];
    #pragma unroll
    for (int fn = 0; fn < 6; fn++){
      int f3 = (fn < 3) ? fn : fn - 3;
      const short8* ib = (fn < 3) ? i0p : i1p;
      bF[0][fn] = ib[bn[f3] * 5 + slc[f3]];
    }

    int rn = 0, sn = 0, r2m = 0;
    #pragma unroll 2
    for (int rs = 0; rs < 81; rs++){
      int cur = rs & 1, nxt = cur ^ 1;
      sn++;
      if (sn == 9){ sn = 0; rn++; r2m += 2; if (r2m >= 5) r2m -= 5; }
      int nrs = (rs < 80) ? rs + 1 : 80;
      int roff = rn * 20 + sn;
      const short8* apn = ap + (size_t)nrs * 2048;
      #pragma unroll
      for (int fo = 0; fo < 4; fo++) aF[nxt][fo] = apn[fo * 64];
      #pragma unroll
      for (int fn = 0; fn < 6; fn++){
        int f3 = (fn < 3) ? fn : fn - 3;
        const short8* ib = (fn < 3) ? i0p : i1p;
        int sl = slc[f3] + r2m; if (sl >= 5) sl -= 5;
        bF[nxt][fn] = ib[(bn[f3] + roff) * 5 + sl];
      }
      #pragma unroll
      for (int fo = 0; fo < 4; fo++)
        #pragma unroll
        for (int fn = 0; fn < 6; fn++)
          acc[fo][fn] = __builtin_amdgcn_mfma_f32_16x16x32_bf16(aF[cur][fo], bF[cur][fn], acc[fo][fn], 0, 0, 0);
    }
  }

  #pragma unroll
  for (int fn = 0; fn < 6; fn++){
    int im = (fn < 3) ? 0 : 1;
    int f3 = (fn < 3) ? fn : fn - 3;
    int pos = f3 * 16 + l15;
    if (pos < 36){
      float* cb = caps4 + ((size_t)kq * 256 + b0 + im) * 9216;
      #pragma unroll
      for (int fo = 0; fo < 4; fo++){
        int ob = wid * 64 + fo * 16 + quad * 4;
        #pragma unroll
        for (int rr = 0; rr < 4; rr++)
          cb[(size_t)(ob + rr) * 36 + pos] = acc[fo][fn][rr];
      }
    }
  }
}

// sum 4 kq-partials + bias, squash -> caps [b][i][8] fp32
__global__ __launch_bounds__(256) void squash4_kernel(const float* __restrict__ caps4,
    const float* __restrict__ bias, float* __restrict__ caps){
  size_t cid = (size_t)blockIdx.x * 256 + threadIdx.x;
  size_t base = cid * 8;
  const size_t STR = 2359296;
  float4 a0 = *(const float4*)(caps4 + base);
  float4 a1 = *(const float4*)(caps4 + base + 4);
  #pragma unroll
  for (int k = 1; k < 4; k++){
    float4 q0 = *(const float4*)(caps4 + k * STR + base);
    float4 q1 = *(const float4*)(caps4 + k * STR + base + 4);
    a0.x+=q0.x; a0.y+=q0.y; a0.z+=q0.z; a0.w+=q0.w;
    a1.x+=q1.x; a1.y+=q1.y; a1.z+=q1.z; a1.w+=q1.w;
  }
  int off = (int)(base % 9216);
  float v[8] = {a0.x,a0.y,a0.z,a0.w,a1.x,a1.y,a1.z,a1.w};
  #pragma unroll
  for (int e = 0; e < 8; e++) v[e] += bias[(off + e) / 36];
  float msq = 0.f;
  #pragma unroll
  for (int e = 0; e < 8; e++) msq += v[e]*v[e];
  float scale = sqrtf(msq) / (1.f + msq);
  float* cp = caps + base;
  #pragma unroll
  for (int e = 0; e < 8; e++) cp[e] = v[e]*scale;
}

// uT[b][jd][i] = sum_k Wrb[jd*8+k][i] * caps[b][i][k]  (bf16 out)
// grid (18 i-chunks, 64 = 16 b-groups x 4 jd-quarters), 2D (graph-replay
// safety: gridDim.z>1 diverged under the harness's graph timing in R9).
__global__ __launch_bounds__(256) void uhat_t_kernel(const float* __restrict__ caps,
    const ushort* __restrict__ Wrb, ushort* __restrict__ uT){
  __shared__ float cl[8 * 16 * 64];   // [k][bb][il], 32 KB
  int i0  = blockIdx.x * 64;
  int by  = blockIdx.y;
  int b0  = (by >> 2) * 16;
  int jd0 = (by & 3) * 40;
  int t = threadIdx.x, lane = t & 63, w = t >> 6;
  for (int f = t; f < 2048; f += 256){
    int base = f * 4; int bb = base >> 9; int r = base & 511;
    int il = r >> 3; int k = r & 7;
    float4 v = *(const float4*)(caps + ((size_t)(b0+bb)*1152 + i0 + il)*8 + k);
    cl[((k+0)*16+bb)*64+il] = v.x;
    cl[((k+1)*16+bb)*64+il] = v.y;
    cl[((k+2)*16+bb)*64+il] = v.z;
    cl[((k+3)*16+bb)*64+il] = v.w;
  }
  __syncthreads();
  for (int jj = 0; jj < 10; jj++){
    int jd = jd0 + w * 10 + jj;
    float wk[8];
    #pragma unroll
    for (int k = 0; k < 8; k++)
      wk[k] = bfu(Wrb[((size_t)jd * 8 + k) * 1152 + i0 + lane]);
    #pragma unroll
    for (int bb = 0; bb < 16; bb++){
      float acc = 0.f;
      #pragma unroll
      for (int k = 0; k < 8; k++) acc = fmaf(wk[k], cl[(k*16+bb)*64+lane], acc);
      __hip_bfloat16 hv = __float2bfloat16(acc);
      uT[((size_t)(b0+bb)*160 + jd)*1152 + i0 + lane] = *(ushort*)&hv;
    }
  }
}

// routing iteration: phase A (dots -> b -> softmax -> c, thread->i) +
// phase B (wave->jd, lanes->2i via uint loads). grid (3 chunks, 256 b).
// mode 0: c uniform 0.1 (phase B only); 1: b=d (write); 2: b+=d (read).
__global__ __launch_bounds__(384) void routeAB_kernel(
    const ushort* __restrict__ uT, const float* __restrict__ vin,
    float* __restrict__ bbuf, float* __restrict__ spart, int mode){
  __shared__ float c_l[384 * 11];
  __shared__ float vs[160];
  int ic = blockIdx.x;   // 0..2
  int b  = blockIdx.y;   // 0..255
  int t = threadIdx.x;
  int lane = t & 63, w = t >> 6;   // 6 waves
  const ushort* ub = uT + (size_t)b * 184320 + ic * 384;

  if (mode){
    if (t < 160) vs[t] = vin[b * 160 + t];
    __syncthreads();
    const ushort* up = ub + t;
    float d[10];
    #pragma unroll
    for (int j = 0; j < 10; j++){
      float dj = 0.f;
      #pragma unroll
      for (int dd = 0; dd < 16; dd++){
        int jd = j * 16 + dd;
        dj = fmaf(bfu(up[(size_t)jd * 1152]), vs[jd], dj);
      }
      d[j] = dj;
    }
    float* bp = bbuf + ((size_t)b * 1152 + ic * 384 + t) * 10;
    if (mode == 2){
      #pragma unroll
      for (int j = 0; j < 10; j++) d[j] += bp[j];
    } else {
      #pragma unroll
      for (int j = 0; j < 10; j++) bp[j] = d[j];
    }
    float m = d[0];
    #pragma unroll
    for (int j = 1; j < 10; j++) m = fmaxf(m, d[j]);
    float se = 0.f;
    #pragma unroll
    for (int j = 0; j < 10; j++){ d[j] = __expf(d[j] - m); se += d[j]; }
    float inv = 1.f / se;
    #pragma unroll
    for (int j = 0; j < 10; j++) c_l[t * 11 + j] = d[j] * inv;
  }
  __syncthreads();

  for (int jd = w; jd < 160; jd += 6){
    const uint* urow32 = (const uint*)(ub + (size_t)jd * 1152);
    float sacc = 0.f;
    if (mode){
      int jj = jd >> 4;
      #pragma unroll
      for (int st = 0; st < 3; st++){
        uint uv = urow32[st * 64 + lane];
        int i_l = (st * 64 + lane) * 2;
        sacc = fmaf(bfu((ushort)(uv & 0xffffu)), c_l[i_l * 11 + jj], sacc);
        sacc = fmaf(bfu((ushort)(uv >> 16)),     c_l[(i_l + 1) * 11 + jj], sacc);
      }
    } else {
      #pragma unroll
      for (int st = 0; st < 3; st++){
        uint uv = urow32[st * 64 + lane];
        sacc += bfu((ushort)(uv & 0xffffu)) + bfu((ushort)(uv >> 16));
      }
    }
    sacc += __shfl_xor(sacc, 32);
    sacc += __shfl_xor(sacc, 16);
    sacc += __shfl_xor(sacc, 8);
    sacc += __shfl_xor(sacc, 4);
    sacc += __shfl_xor(sacc, 2);
    sacc += __shfl_xor(sacc, 1);
    if (lane == 0) spart[((size_t)ic * 256 + b) * 160 + jd] = mode ? sacc : sacc * 0.1f;
  }
}

// sum 3 chunk partials + bias, squash over 16-groups -> v (or final out)
__global__ __launch_bounds__(160) void vsq_kernel(const float* __restrict__ spart,
    const float* __restrict__ dcb, float* __restrict__ vout){
  int b = blockIdx.x;
  int t = threadIdx.x;   // 0..159
  float s = dcb[t];
  #pragma unroll
  for (int ic = 0; ic < 3; ic++) s += spart[((size_t)ic * 256 + b) * 160 + t];
  float msq = s * s;
  msq += __shfl_xor(msq, 1, 16);
  msq += __shfl_xor(msq, 2, 16);
  msq += __shfl_xor(msq, 4, 16);
  msq += __shfl_xor(msq, 8, 16);
  float scale = sqrtf(msq) / (1.f + msq);
  vout[b * 160 + t] = s * scale;
}

extern "C" void kernel_launch(void* const* d_in, const int* in_sizes, int n_in,
                              void* d_out, int out_size, void* d_ws, size_t ws_size,
                              hipStream_t stream){
  (void)in_sizes; (void)n_in; (void)out_size; (void)ws_size;
  const float* x   = (const float*)d_in[0];
  const float* w1  = (const float*)d_in[1];
  const float* b1  = (const float*)d_in[2];
  const float* w2  = (const float*)d_in[3];
  const float* b2  = (const float*)d_in[4];
  const float* W   = (const float*)d_in[5];
  const float* dcb = (const float*)d_in[6];
  float* out = (float*)d_out;

  char* ws = (char*)d_ws;
  __hip_bfloat16* ht = (__hip_bfloat16*)(ws);
  ushort* A2s  = (ushort*)(ws + 52428800);
  float* caps4 = (float*)(ws + 63045632);
  ushort* uT   = (ushort*)(ws);                  // overlays ht/A2/caps4 (dead)
  float* caps  = (float*)(ws + 100794368);
  ushort* Wrb  = (ushort*)(ws + 110231552);
  float* bbuf  = (float*)(ws + 113180672);
  float* spart = (float*)(ws + 124977152);
  float* vbuf  = (float*)(ws + 125468672);

  conv1_kernel<<<dim3(256, 8), 640, 0, stream>>>(x, w1, b1, ht);
  arepack_kernel<<<256, 256, 0, stream>>>(w2, A2s);
  wrepack_kernel<<<dim3(18, 20), 256, 0, stream>>>(W, Wrb);
  conv2_mfma_kernel<<<512, 256, 0, stream>>>(ht, (const short8*)A2s, caps4);
  squash4_kernel<<<1152, 256, 0, stream>>>(caps4, b2, caps);
  uhat_t_kernel<<<dim3(18, 64), 256, 0, stream>>>(caps, Wrb, uT);
  routeAB_kernel<<<dim3(3, 256), 384, 0, stream>>>(uT, vbuf, bbuf, spart, 0);
  vsq_kernel<<<256, 160, 0, stream>>>(spart, dcb, vbuf);
  routeAB_kernel<<<dim3(3, 256), 384, 0, stream>>>(uT, vbuf, bbuf, spart, 1);
  vsq_kernel<<<256, 160, 0, stream>>>(spart, dcb, vbuf);
  routeAB_kernel<<<dim3(3, 256), 384, 0, stream>>>(uT, vbuf, bbuf, spart, 2);
  vsq_kernel<<<256, 160, 0, stream>>>(spart, dcb, out);
}

// Round 10
// 397.714 us; speedup vs baseline: 3.1178x; 1.0473x over previous
//
#include <hip/hip_runtime.h>
#include <hip/hip_bf16.h>

// ---------------------------------------------------------------------------
// CapsuleNet forward. Round 20: R0 pipeline + conv2 A-prefetch depth 2.
//  R19 re-verified the R0 baseline (416 us this node; conv2 126 us,
//  MfmaUtil 47%, occupancy 19.5% with LDS and regfile both binding at
//  2 waves/SIMD). At that occupancy the 1-iteration prefetch distance
//  (~100-140 cyc issue window) cannot cover A's ~200 cyc L2-hit latency.
//  Change (conv2 only, structure preserved): aF[4][4] register slots,
//  consume slot rs&3, load slot (rs+2)&3 two iterations ahead;
//  #pragma unroll 4 folds all slot indices to constants (no scratch);
//  80 = 4x20 loop + peeled rs=80 tail. B path byte-identical (bF[2][6],
//  1-ahead; LDS latency is covered). +32 VGPR -> ~124+96 AGPR = 220 < 256,
//  occupancy unchanged. Same loads, same MFMA order, same numerics.
// Everything else byte-identical to Round 19 (= Round 0).
//
// Workspace (bytes), total ~125.6 MB:
//   ht    @ 0           : 52,428,800  (conv phase)
//   A2    @ 52,428,800  : 10,616,832 -> 63,045,632
//   caps4 @ 63,045,632  : 37,748,736 -> 100,794,368
//   uT    @ 0           : 94,371,840  (overlays ht/A2/caps4)
//   caps  @ 100,794,368 : 9,437,184  -> 110,231,552
//   Wrb   @ 110,231,552 : 2,949,120  -> 113,180,672
//   bbuf  @ 113,180,672 : 11,796,480 -> 124,977,152
//   spart @ 124,977,152 : 491,520    -> 125,468,672
//   vbuf  @ 125,468,672 : 163,840    -> 125,632,512
// ---------------------------------------------------------------------------

typedef __attribute__((ext_vector_type(8))) short short8;
typedef __attribute__((ext_vector_type(4))) float float4v;

__device__ inline float bfu(ushort v){ return __uint_as_float((unsigned)v << 16); }

// conv1: x[256,1,28,28] * w[256,1,9,9] -> h_t[b][pos 400][c 256] bf16
__global__ __launch_bounds__(640) void conv1_kernel(const float* __restrict__ x,
    const float* __restrict__ w, const float* __restrict__ bias,
    __hip_bfloat16* __restrict__ ht){
  __shared__ float img[784];
  __shared__ float wsv[32 * 81];
  __shared__ ushort tile[400 * 33];
  int b = blockIdx.x;
  int og = blockIdx.y;
  int t = threadIdx.x;
  const float* xb = x + (size_t)b * 784;
  for (int idx = t; idx < 784; idx += 640) img[idx] = xb[idx];
  for (int idx = t; idx < 2592; idx += 640) wsv[idx] = w[(size_t)og * 2592 + idx];
  __syncthreads();
  int o_l = t / 20;
  int y   = t - o_l * 20;
  float acc[20];
  #pragma unroll
  for (int i = 0; i < 20; i++) acc[i] = 0.f;
  #pragma unroll
  for (int r = 0; r < 9; r++){
    float row[28];
    const float4* rp = (const float4*)&img[(y + r) * 28];
    #pragma unroll
    for (int q = 0; q < 7; q++){
      float4 v4 = rp[q];
      row[4*q+0]=v4.x; row[4*q+1]=v4.y; row[4*q+2]=v4.z; row[4*q+3]=v4.w;
    }
    #pragma unroll
    for (int s = 0; s < 9; s++){
      float wv = wsv[o_l * 81 + r * 9 + s];
      #pragma unroll
      for (int xx = 0; xx < 20; xx++)
        acc[xx] = fmaf(wv, row[xx + s], acc[xx]);
    }
  }
  float bv = bias[og * 32 + o_l];
  #pragma unroll
  for (int xx = 0; xx < 20; xx++){
    __hip_bfloat16 hv = __float2bfloat16(acc[xx] + bv);
    tile[(y * 20 + xx) * 33 + o_l] = *(ushort*)&hv;
  }
  __syncthreads();
  __hip_bfloat16* hb = ht + (size_t)b * 102400 + og * 32;
  for (int idx = t; idx < 6400; idx += 640){
    int pos = idx >> 4, op = idx & 15;
    unsigned v = (unsigned)tile[pos * 33 + op * 2]
               | ((unsigned)tile[pos * 33 + op * 2 + 1] << 16);
    *(unsigned*)(hb + (size_t)pos * 256 + op * 2) = v;
  }
}

// repack conv2 weights (wave-tiled)
__global__ __launch_bounds__(256) void arepack_kernel(const float* __restrict__ w2,
    ushort* __restrict__ A2s){
  __shared__ float wbuf[64 * 81];
  int o = blockIdx.x;
  int t = threadIdx.x;
  int ow = o >> 6, fo = (o >> 4) & 3, l15 = o & 15;
  size_t obase8 = (size_t)ow * 165888 + (size_t)fo * 64 + (size_t)l15 * 4;
  for (int c0 = 0; c0 < 256; c0 += 64){
    __syncthreads();
    for (int idx = t; idx < 5184; idx += 256)
      wbuf[idx] = w2[(size_t)o * 20736 + (size_t)c0 * 81 + idx];
    __syncthreads();
    for (int idx = t; idx < 2592; idx += 256){
      int rs = idx >> 5;
      int cp = (idx & 31) * 2;
      int cg = c0 + cp;
      int ct = cg >> 5, quad = (cg >> 3) & 3, e = cg & 7;
      __hip_bfloat16 b0 = __float2bfloat16(wbuf[cp * 81 + rs]);
      __hip_bfloat16 b1 = __float2bfloat16(wbuf[(cp + 1) * 81 + rs]);
      unsigned pack = (unsigned)*(ushort*)&b0 | ((unsigned)*(ushort*)&b1 << 16);
      size_t si = (obase8 + (size_t)ct * 256 + (size_t)rs * 2048 + quad) * 8 + e;
      *(unsigned*)(A2s + si) = pack;
    }
  }
}

// W [1152][1280] f32 -> Wrb [1280][1152] bf16 (transposed)
__global__ __launch_bounds__(256) void wrepack_kernel(const float* __restrict__ W,
    ushort* __restrict__ Wrb){
  __shared__ float tile[64][65];
  int r0 = blockIdx.x * 64;  // i
  int c0 = blockIdx.y * 64;  // jdk
  int t = threadIdx.x; int lx = t & 63, ly = t >> 6;
  for (int rr = ly; rr < 64; rr += 4)
    tile[rr][lx] = W[(size_t)(r0 + rr) * 1280 + c0 + lx];
  __syncthreads();
  for (int rr = ly; rr < 64; rr += 4){
    __hip_bfloat16 hv = __float2bfloat16(tile[lx][rr]);
    Wrb[(size_t)(c0 + rr) * 1152 + r0 + lx] = *(ushort*)&hv;
  }
}

// conv2 implicit GEMM, 2 images/block; A-prefetch depth 2 (4 reg slots).
__global__ __launch_bounds__(256, 2) void conv2_mfma_kernel(
    const __hip_bfloat16* __restrict__ ht, const short8* __restrict__ A2,
    float* __restrict__ caps4){
  __shared__ ushort img[2][400 * 40];
  int bx  = blockIdx.x;
  int xcd = bx & 7;
  int kq  = xcd >> 1;
  int p   = ((bx >> 3) << 1) | (xcd & 1);
  int b0  = p * 2;
  int t = threadIdx.x;
  int lane = t & 63;
  int wid  = t >> 6;
  int l15  = lane & 15;
  int quad = lane >> 4;

  int bn[3], slc[3];
  #pragma unroll
  for (int fn = 0; fn < 3; fn++){
    int n = fn * 16 + l15;
    int y = n / 6, xx = n - y * 6;
    if (n >= 36){ y = 0; xx = 0; }
    bn[fn]  = 40 * y + 2 * xx;
    slc[fn] = (quad + 4 * y) % 5;
  }
  const short8* i0p = (const short8*)&img[0][0];
  const short8* i1p = (const short8*)&img[1][0];

  float4v acc[4][6];
  #pragma unroll
  for (int fo = 0; fo < 4; fo++)
    #pragma unroll
    for (int fn = 0; fn < 6; fn++)
      acc[fo][fn] = (float4v){0.f, 0.f, 0.f, 0.f};

  for (int ci = 0; ci < 2; ci++){
    int ct = kq * 2 + ci;
    __syncthreads();
    #pragma unroll
    for (int im = 0; im < 2; im++){
      const __hip_bfloat16* hb = ht + (size_t)(b0 + im) * 102400;
      for (int idx = t; idx < 1600; idx += 256){
        int pp = idx >> 2, q = idx & 3;
        int sl = (q + 2 * (pp / 20)) % 5;
        uint4 v = *(const uint4*)(hb + (size_t)pp * 256 + ct * 32 + q * 8);
        *(uint4*)&img[im][pp * 40 + sl * 8] = v;
      }
    }
    __syncthreads();

    const short8* ap = A2 + ((size_t)wid * 648 + ct) * 256 + l15 * 4 + quad;

    short8 aF[4][4], bF[2][6];
    // prologue: A for rs=0 (slot 0) and rs=1 (slot 1); B for rs=0 (slot 0)
    #pragma unroll
    for (int fo = 0; fo < 4; fo++) aF[0][fo] = ap[fo * 64];
    #pragma unroll
    for (int fo = 0; fo < 4; fo++) aF[1][fo] = ap[2048 + fo * 64];
    #pragma unroll
    for (int fn = 0; fn < 6; fn++){
      int f3 = (fn < 3) ? fn : fn - 3;
      const short8* ib = (fn < 3) ? i0p : i1p;
      bF[0][fn] = ib[bn[f3] * 5 + slc[f3]];
    }

    int rn = 0, sn = 0, r2m = 0;   // B-state: describes rs (advanced to rs+1 in-loop)
    #pragma unroll 4
    for (int rs = 0; rs < 80; rs++){
      // advance B-state to rs+1
      sn++;
      if (sn == 9){ sn = 0; rn++; r2m += 2; if (r2m >= 5) r2m -= 5; }
      int roff = rn * 20 + sn;
      // A two ahead (clamped), B one ahead
      int nrs2 = (rs < 78) ? rs + 2 : 80;
      const short8* apn = ap + (size_t)nrs2 * 2048;
      int la = (rs + 2) & 3, lb = (rs + 1) & 1;
      int ca = rs & 3,       cb = rs & 1;
      #pragma unroll
      for (int fo = 0; fo < 4; fo++) aF[la][fo] = apn[fo * 64];
      #pragma unroll
      for (int fn = 0; fn < 6; fn++){
        int f3 = (fn < 3) ? fn : fn - 3;
        const short8* ib = (fn < 3) ? i0p : i1p;
        int sl = slc[f3] + r2m; if (sl >= 5) sl -= 5;
        bF[lb][fn] = ib[(bn[f3] + roff) * 5 + sl];
      }
      #pragma unroll
      for (int fo = 0; fo < 4; fo++)
        #pragma unroll
        for (int fn = 0; fn < 6; fn++)
          acc[fo][fn] = __builtin_amdgcn_mfma_f32_16x16x32_bf16(aF[ca][fo], bF[cb][fn], acc[fo][fn], 0, 0, 0);
    }
    // tail rs=80: A slot 80&3=0 (loaded at rs=78), B slot 80&1=0 (loaded at rs=79)
    #pragma unroll
    for (int fo = 0; fo < 4; fo++)
      #pragma unroll
      for (int fn = 0; fn < 6; fn++)
        acc[fo][fn] = __builtin_amdgcn_mfma_f32_16x16x32_bf16(aF[0][fo], bF[0][fn], acc[fo][fn], 0, 0, 0);
  }

  #pragma unroll
  for (int fn = 0; fn < 6; fn++){
    int im = (fn < 3) ? 0 : 1;
    int f3 = (fn < 3) ? fn : fn - 3;
    int pos = f3 * 16 + l15;
    if (pos < 36){
      float* cb = caps4 + ((size_t)kq * 256 + b0 + im) * 9216;
      #pragma unroll
      for (int fo = 0; fo < 4; fo++){
        int ob = wid * 64 + fo * 16 + quad * 4;
        #pragma unroll
        for (int rr = 0; rr < 4; rr++)
          cb[(size_t)(ob + rr) * 36 + pos] = acc[fo][fn][rr];
      }
    }
  }
}

// sum 4 kq-partials + bias, squash -> caps [b][i][8] fp32
__global__ __launch_bounds__(256) void squash4_kernel(const float* __restrict__ caps4,
    const float* __restrict__ bias, float* __restrict__ caps){
  size_t cid = (size_t)blockIdx.x * 256 + threadIdx.x;
  size_t base = cid * 8;
  const size_t STR = 2359296;
  float4 a0 = *(const float4*)(caps4 + base);
  float4 a1 = *(const float4*)(caps4 + base + 4);
  #pragma unroll
  for (int k = 1; k < 4; k++){
    float4 q0 = *(const float4*)(caps4 + k * STR + base);
    float4 q1 = *(const float4*)(caps4 + k * STR + base + 4);
    a0.x+=q0.x; a0.y+=q0.y; a0.z+=q0.z; a0.w+=q0.w;
    a1.x+=q1.x; a1.y+=q1.y; a1.z+=q1.z; a1.w+=q1.w;
  }
  int off = (int)(base % 9216);
  float v[8] = {a0.x,a0.y,a0.z,a0.w,a1.x,a1.y,a1.z,a1.w};
  #pragma unroll
  for (int e = 0; e < 8; e++) v[e] += bias[(off + e) / 36];
  float msq = 0.f;
  #pragma unroll
  for (int e = 0; e < 8; e++) msq += v[e]*v[e];
  float scale = sqrtf(msq) / (1.f + msq);
  float* cp = caps + base;
  #pragma unroll
  for (int e = 0; e < 8; e++) cp[e] = v[e]*scale;
}

// uT[b][jd][i] = sum_k Wrb[jd*8+k][i] * caps[b][i][k]  (bf16 out)
// grid (18 i-chunks, 64 = 16 b-groups x 4 jd-quarters), 2D (graph-replay
// safety: gridDim.z>1 diverged under the harness's graph timing in R9).
__global__ __launch_bounds__(256) void uhat_t_kernel(const float* __restrict__ caps,
    const ushort* __restrict__ Wrb, ushort* __restrict__ uT){
  __shared__ float cl[8 * 16 * 64];   // [k][bb][il], 32 KB
  int i0  = blockIdx.x * 64;
  int by  = blockIdx.y;
  int b0  = (by >> 2) * 16;
  int jd0 = (by & 3) * 40;
  int t = threadIdx.x, lane = t & 63, w = t >> 6;
  for (int f = t; f < 2048; f += 256){
    int base = f * 4; int bb = base >> 9; int r = base & 511;
    int il = r >> 3; int k = r & 7;
    float4 v = *(const float4*)(caps + ((size_t)(b0+bb)*1152 + i0 + il)*8 + k);
    cl[((k+0)*16+bb)*64+il] = v.x;
    cl[((k+1)*16+bb)*64+il] = v.y;
    cl[((k+2)*16+bb)*64+il] = v.z;
    cl[((k+3)*16+bb)*64+il] = v.w;
  }
  __syncthreads();
  for (int jj = 0; jj < 10; jj++){
    int jd = jd0 + w * 10 + jj;
    float wk[8];
    #pragma unroll
    for (int k = 0; k < 8; k++)
      wk[k] = bfu(Wrb[((size_t)jd * 8 + k) * 1152 + i0 + lane]);
    #pragma unroll
    for (int bb = 0; bb < 16; bb++){
      float acc = 0.f;
      #pragma unroll
      for (int k = 0; k < 8; k++) acc = fmaf(wk[k], cl[(k*16+bb)*64+lane], acc);
      __hip_bfloat16 hv = __float2bfloat16(acc);
      uT[((size_t)(b0+bb)*160 + jd)*1152 + i0 + lane] = *(ushort*)&hv;
    }
  }
}

// routing iteration: phase A (dots -> b -> softmax -> c, thread->i) +
// phase B (wave->jd, lanes->2i via uint loads). grid (3 chunks, 256 b).
// mode 0: c uniform 0.1 (phase B only); 1: b=d (write); 2: b+=d (read).
__global__ __launch_bounds__(384) void routeAB_kernel(
    const ushort* __restrict__ uT, const float* __restrict__ vin,
    float* __restrict__ bbuf, float* __restrict__ spart, int mode){
  __shared__ float c_l[384 * 11];
  __shared__ float vs[160];
  int ic = blockIdx.x;   // 0..2
  int b  = blockIdx.y;   // 0..255
  int t = threadIdx.x;
  int lane = t & 63, w = t >> 6;   // 6 waves
  const ushort* ub = uT + (size_t)b * 184320 + ic * 384;

  if (mode){
    if (t < 160) vs[t] = vin[b * 160 + t];
    __syncthreads();
    const ushort* up = ub + t;
    float d[10];
    #pragma unroll
    for (int j = 0; j < 10; j++){
      float dj = 0.f;
      #pragma unroll
      for (int dd = 0; dd < 16; dd++){
        int jd = j * 16 + dd;
        dj = fmaf(bfu(up[(size_t)jd * 1152]), vs[jd], dj);
      }
      d[j] = dj;
    }
    float* bp = bbuf + ((size_t)b * 1152 + ic * 384 + t) * 10;
    if (mode == 2){
      #pragma unroll
      for (int j = 0; j < 10; j++) d[j] += bp[j];
    } else {
      #pragma unroll
      for (int j = 0; j < 10; j++) bp[j] = d[j];
    }
    float m = d[0];
    #pragma unroll
    for (int j = 1; j < 10; j++) m = fmaxf(m, d[j]);
    float se = 0.f;
    #pragma unroll
    for (int j = 0; j < 10; j++){ d[j] = __expf(d[j] - m); se += d[j]; }
    float inv = 1.f / se;
    #pragma unroll
    for (int j = 0; j < 10; j++) c_l[t * 11 + j] = d[j] * inv;
  }
  __syncthreads();

  for (int jd = w; jd < 160; jd += 6){
    const uint* urow32 = (const uint*)(ub + (size_t)jd * 1152);
    float sacc = 0.f;
    if (mode){
      int jj = jd >> 4;
      #pragma unroll
      for (int st = 0; st < 3; st++){
        uint uv = urow32[st * 64 + lane];
        int i_l = (st * 64 + lane) * 2;
        sacc = fmaf(bfu((ushort)(uv & 0xffffu)), c_l[i_l * 11 + jj], sacc);
        sacc = fmaf(bfu((ushort)(uv >> 16)),     c_l[(i_l + 1) * 11 + jj], sacc);
      }
    } else {
      #pragma unroll
      for (int st = 0; st < 3; st++){
        uint uv = urow32[st * 64 + lane];
        sacc += bfu((ushort)(uv & 0xffffu)) + bfu((ushort)(uv >> 16));
      }
    }
    sacc += __shfl_xor(sacc, 32);
    sacc += __shfl_xor(sacc, 16);
    sacc += __shfl_xor(sacc, 8);
    sacc += __shfl_xor(sacc, 4);
    sacc += __shfl_xor(sacc, 2);
    sacc += __shfl_xor(sacc, 1);
    if (lane == 0) spart[((size_t)ic * 256 + b) * 160 + jd] = mode ? sacc : sacc * 0.1f;
  }
}

// sum 3 chunk partials + bias, squash over 16-groups -> v (or final out)
__global__ __launch_bounds__(160) void vsq_kernel(const float* __restrict__ spart,
    const float* __restrict__ dcb, float* __restrict__ vout){
  int b = blockIdx.x;
  int t = threadIdx.x;   // 0..159
  float s = dcb[t];
  #pragma unroll
  for (int ic = 0; ic < 3; ic++) s += spart[((size_t)ic * 256 + b) * 160 + t];
  float msq = s * s;
  msq += __shfl_xor(msq, 1, 16);
  msq += __shfl_xor(msq, 2, 16);
  msq += __shfl_xor(msq, 4, 16);
  msq += __shfl_xor(msq, 8, 16);
  float scale = sqrtf(msq) / (1.f + msq);
  vout[b * 160 + t] = s * scale;
}

extern "C" void kernel_launch(void* const* d_in, const int* in_sizes, int n_in,
                              void* d_out, int out_size, void* d_ws, size_t ws_size,
                              hipStream_t stream){
  (void)in_sizes; (void)n_in; (void)out_size; (void)ws_size;
  const float* x   = (const float*)d_in[0];
  const float* w1  = (const float*)d_in[1];
  const float* b1  = (const float*)d_in[2];
  const float* w2  = (const float*)d_in[3];
  const float* b2  = (const float*)d_in[4];
  const float* W   = (const float*)d_in[5];
  const float* dcb = (const float*)d_in[6];
  float* out = (float*)d_out;

  char* ws = (char*)d_ws;
  __hip_bfloat16* ht = (__hip_bfloat16*)(ws);
  ushort* A2s  = (ushort*)(ws + 52428800);
  float* caps4 = (float*)(ws + 63045632);
  ushort* uT   = (ushort*)(ws);                  // overlays ht/A2/caps4 (dead)
  float* caps  = (float*)(ws + 100794368);
  ushort* Wrb  = (ushort*)(ws + 110231552);
  float* bbuf  = (float*)(ws + 113180672);
  float* spart = (float*)(ws + 124977152);
  float* vbuf  = (float*)(ws + 125468672);

  conv1_kernel<<<dim3(256, 8), 640, 0, stream>>>(x, w1, b1, ht);
  arepack_kernel<<<256, 256, 0, stream>>>(w2, A2s);
  wrepack_kernel<<<dim3(18, 20), 256, 0, stream>>>(W, Wrb);
  conv2_mfma_kernel<<<512, 256, 0, stream>>>(ht, (const short8*)A2s, caps4);
  squash4_kernel<<<1152, 256, 0, stream>>>(caps4, b2, caps);
  uhat_t_kernel<<<dim3(18, 64), 256, 0, stream>>>(caps, Wrb, uT);
  routeAB_kernel<<<dim3(3, 256), 384, 0, stream>>>(uT, vbuf, bbuf, spart, 0);
  vsq_kernel<<<256, 160, 0, stream>>>(spart, dcb, vbuf);
  routeAB_kernel<<<dim3(3, 256), 384, 0, stream>>>(uT, vbuf, bbuf, spart, 1);
  vsq_kernel<<<256, 160, 0, stream>>>(spart, dcb, vbuf);
  routeAB_kernel<<<dim3(3, 256), 384, 0, stream>>>(uT, vbuf, bbuf, spart, 2);
  vsq_kernel<<<256, 160, 0, stream>>>(spart, dcb, out);
}